// Round 5
// baseline (242.911 us; speedup 1.0000x reference)
//
#include <hip/hip_runtime.h>
#include <math.h>

#define NBINS 15
#define THREADS 256
#define GRID 1536            // 6 blocks/CU * 256 CUs, exact residency at launch_bounds(256,6)
#define BIN_LO 4             // C=3 => conf >= 1/3 => bins 4..14 only
#define NACC (NBINS - BIN_LO)
#define CTR_OFF (NACC * GRID * sizeof(float))  // counter after partials in d_ws

__device__ __forceinline__ void process_row(float l0, float l1, float l2, int lab,
                                            float* a) {
  float m  = fmaxf(fmaxf(l0, l1), l2);            // v_max3_f32
  float md = __builtin_amdgcn_fmed3f(l0, l1, l2); // median
  float mn = fminf(fminf(l0, l1), l2);            // v_min3_f32
  float s  = 1.0f + __expf(md - m) + __expf(mn - m);  // exp(max-max)=1 for free
  float conf = __builtin_amdgcn_rcpf(s);
  // correct <=> logit[label] equals the max (ties measure-zero; ECE effect ~6e-8)
  float lm = (lab == 1) ? l1 : ((lab == 2) ? l2 : l0);
  float val = conf - ((lm >= m) ? 1.0f : 0.0f);
  // bin i covers (i/15,(i+1)/15]; searchsorted(uppers,conf,'left') == ceil(conf*15)-1
  int bin = (int)ceilf(conf * 15.0f) - 1;
  bin = bin < BIN_LO ? BIN_LO : (bin > NBINS - 1 ? NBINS - 1 : bin);
#pragma unroll
  for (int b = BIN_LO; b < NBINS; ++b) a[b - BIN_LO] += (bin == b) ? val : 0.0f;
}

__global__ __launch_bounds__(THREADS, 6) void ece_fused(
    const float4* __restrict__ logits4, const int4* __restrict__ labels4,
    float* __restrict__ partial, unsigned int* __restrict__ ctr,
    float* __restrict__ out, int n) {
  float a[NACC];
#pragma unroll
  for (int i = 0; i < NACC; ++i) a[i] = 0.0f;

  const int nquads = n >> 2;
  const int total = gridDim.x * blockDim.x;
  // 2-deep register prefetch: A = current, B = +1, C = +2 issued before processing A
  int qA = blockIdx.x * blockDim.x + threadIdx.x;
  bool vA = qA < nquads;
  float4 xA, yA, zA; int4 lA;
  if (vA) { const float4* p = logits4 + 3 * (size_t)qA; xA = p[0]; yA = p[1]; zA = p[2]; lA = labels4[qA]; }
  int qB = qA + total; bool vB = qB < nquads;
  float4 xB, yB, zB; int4 lB;
  if (vB) { const float4* p = logits4 + 3 * (size_t)qB; xB = p[0]; yB = p[1]; zB = p[2]; lB = labels4[qB]; }
  while (vA) {
    const int qC = qB + total; const bool vC = qC < nquads;
    float4 xC, yC, zC; int4 lC;
    if (vC) { const float4* p = logits4 + 3 * (size_t)qC; xC = p[0]; yC = p[1]; zC = p[2]; lC = labels4[qC]; }
    process_row(xA.x, xA.y, xA.z, lA.x, a);
    process_row(xA.w, yA.x, yA.y, lA.y, a);
    process_row(yA.z, yA.w, zA.x, lA.z, a);
    process_row(zA.y, zA.z, zA.w, lA.w, a);
    xA = xB; yA = yB; zA = zB; lA = lB; vA = vB;
    xB = xC; yB = yC; zB = zC; lB = lC; vB = vC; qB = qC;
  }

  // wave butterfly reduce, then cross-wave via tiny LDS
#pragma unroll
  for (int i = 0; i < NACC; ++i) {
    float v = a[i];
#pragma unroll
    for (int off = 32; off > 0; off >>= 1) v += __shfl_down(v, off, 64);
    a[i] = v;
  }
  __shared__ float s_part[THREADS / 64][NACC];
  __shared__ bool s_last;
  const int wave = threadIdx.x >> 6;
  const int lane = threadIdx.x & 63;
  if (lane == 0) {
#pragma unroll
    for (int i = 0; i < NACC; ++i) s_part[wave][i] = a[i];
  }
  __syncthreads();
  if (threadIdx.x < NACC) {
    float v = 0.0f;
#pragma unroll
    for (int w = 0; w < THREADS / 64; ++w) v += s_part[w][threadIdx.x];
    partial[(size_t)threadIdx.x * gridDim.x + blockIdx.x] = v;
  }
  // release: make partial[] visible device-wide, then signal (rocPRIM pattern)
  __threadfence();
  __syncthreads();
  if (threadIdx.x == 0) {
    unsigned int old = atomicAdd(ctr, 1u);
    s_last = (old == gridDim.x - 1);
  }
  __syncthreads();
  if (!s_last) return;
  __threadfence();  // acquire side

  // ---- final reduce, runs in exactly one block ----
  __shared__ double sbin[NACC];
  for (int b = wave; b < NACC; b += THREADS / 64) {
    const float* pb = partial + (size_t)b * gridDim.x;
    double v = 0.0;
    for (int i = lane; i < gridDim.x; i += 64) v += (double)pb[i];
#pragma unroll
    for (int off = 32; off > 0; off >>= 1) v += __shfl_down(v, off, 64);
    if (lane == 0) sbin[b] = v;
  }
  __syncthreads();
  if (threadIdx.x == 0) {
    // tail rows if n % 4 != 0 (none for N=2^24)
    float t[NACC];
#pragma unroll
    for (int i = 0; i < NACC; ++i) t[i] = 0.0f;
    const float* lf = (const float*)logits4;
    const int* li = (const int*)labels4;
    for (int r = (n >> 2) << 2; r < n; ++r)
      process_row(lf[3 * r], lf[3 * r + 1], lf[3 * r + 2], li[r], t);
    double ece = 0.0;
#pragma unroll
    for (int b = 0; b < NACC; ++b) ece += fabs(sbin[b] + (double)t[b]);
    out[0] = (float)(ece / (double)n);
  }
}

extern "C" void kernel_launch(void* const* d_in, const int* in_sizes, int n_in,
                              void* d_out, int out_size, void* d_ws, size_t ws_size,
                              hipStream_t stream) {
  const float4* logits4 = (const float4*)d_in[0];
  const int4* labels4 = (const int4*)d_in[1];
  const int n = in_sizes[1];  // rows == number of labels
  float* partial = (float*)d_ws;                          // [NACC][GRID]
  unsigned int* ctr = (unsigned int*)((char*)d_ws + CTR_OFF);
  hipMemsetAsync(ctr, 0, sizeof(unsigned int), stream);   // counter must start at 0
  ece_fused<<<GRID, THREADS, 0, stream>>>(logits4, labels4, partial, ctr,
                                          (float*)d_out, n);
}

// Round 6
// 66.469 us; speedup vs baseline: 3.6545x; 3.6545x over previous
//
#include <hip/hip_runtime.h>
#include <math.h>

#define NBINS 15
#define THREADS 256
#define GRID 2048          // 8 blocks/CU * 256 CUs; exactly 8 iters/thread at N=2^24
#define BIN_LO 4           // C=3 => conf >= 1/3 => bins 4..14 only
#define NACC (NBINS - BIN_LO)

struct Accum {
  double d[NACC];  // sum over bin of (conf - correct); ECE = sum |d[b]| / n
};

__device__ __forceinline__ void process_row(float l0, float l1, float l2, int lab,
                                            float* a) {
  float m  = fmaxf(fmaxf(l0, l1), l2);            // v_max3_f32
  float md = __builtin_amdgcn_fmed3f(l0, l1, l2); // median
  float mn = fminf(fminf(l0, l1), l2);            // v_min3_f32
  float s  = 1.0f + __expf(md - m) + __expf(mn - m);  // exp(max-max)=1 for free
  float conf = __builtin_amdgcn_rcpf(s);          // max prob = 1/s
  // correct <=> logit[label] equals the max (ties measure-zero; ECE effect ~6e-8)
  float lm = (lab == 1) ? l1 : ((lab == 2) ? l2 : l0);
  float val = conf - ((lm >= m) ? 1.0f : 0.0f);
  // bin i covers (i/15,(i+1)/15]; searchsorted(uppers,conf,'left') == ceil(conf*15)-1
  int bin = (int)ceilf(conf * 15.0f) - 1;
  bin = bin < BIN_LO ? BIN_LO : (bin > NBINS - 1 ? NBINS - 1 : bin);
#pragma unroll
  for (int b = BIN_LO; b < NBINS; ++b) a[b - BIN_LO] += (bin == b) ? val : 0.0f;
}

__global__ __launch_bounds__(THREADS, 8) void ece_main(
    const float4* __restrict__ logits4, const int4* __restrict__ labels4,
    Accum* __restrict__ ws, int n) {
  float a[NACC];
#pragma unroll
  for (int i = 0; i < NACC; ++i) a[i] = 0.0f;

  const int nquads = n >> 2;
  const int total = gridDim.x * blockDim.x;
  int q = blockIdx.x * blockDim.x + threadIdx.x;
  if (q < nquads) {
    // single-deep prefetch: loads for iter k+1 issued before processing iter k
    float4 x = logits4[3 * (size_t)q + 0];
    float4 y = logits4[3 * (size_t)q + 1];
    float4 z = logits4[3 * (size_t)q + 2];
    int4 lb = labels4[q];
    for (;;) {
      const int qn = q + total;
      const bool more = qn < nquads;
      float4 xn, yn, zn;
      int4 lbn;
      if (more) {
        xn = logits4[3 * (size_t)qn + 0];
        yn = logits4[3 * (size_t)qn + 1];
        zn = logits4[3 * (size_t)qn + 2];
        lbn = labels4[qn];
      }
      process_row(x.x, x.y, x.z, lb.x, a);
      process_row(x.w, y.x, y.y, lb.y, a);
      process_row(y.z, y.w, z.x, lb.z, a);
      process_row(z.y, z.z, z.w, lb.w, a);
      if (!more) break;
      x = xn; y = yn; z = zn; lb = lbn; q = qn;
    }
  }

  // wave butterfly reduce, then cross-wave via tiny LDS
#pragma unroll
  for (int i = 0; i < NACC; ++i) {
    float v = a[i];
#pragma unroll
    for (int off = 32; off > 0; off >>= 1) v += __shfl_down(v, off, 64);
    a[i] = v;
  }
  __shared__ float s_part[THREADS / 64][NACC];
  const int wave = threadIdx.x >> 6;
  const int lane = threadIdx.x & 63;
  if (lane == 0) {
#pragma unroll
    for (int i = 0; i < NACC; ++i) s_part[wave][i] = a[i];
  }
  __syncthreads();
  if (threadIdx.x < NACC) {
    float v = 0.0f;
#pragma unroll
    for (int w = 0; w < THREADS / 64; ++w) v += s_part[w][threadIdx.x];
    atomicAdd(&ws->d[threadIdx.x], (double)v);  // device-scope, 11 addrs total
  }
}

__global__ void ece_final(const Accum* __restrict__ ws, const float* __restrict__ logits,
                          const int* __restrict__ labels, float* __restrict__ out,
                          int n) {
  // single wave: lane b < NACC holds |d[b]|, butterfly-sum, lane 0 writes
  double v = 0.0;
  if (threadIdx.x < NACC) v = fabs(ws->d[threadIdx.x]);
  // tail rows if n % 4 != 0 (none for N=2^24)
  if (threadIdx.x == 0) {
    float t[NACC];
#pragma unroll
    for (int i = 0; i < NACC; ++i) t[i] = 0.0f;
    for (int r = (n >> 2) << 2; r < n; ++r)
      process_row(logits[3 * r], logits[3 * r + 1], logits[3 * r + 2], labels[r], t);
    // fold tail into lane 0's |d| contribution conservatively: recompute with tail
    // (tail is empty in the benchmark shape; this branch is cold)
    if (((n >> 2) << 2) != n) {
      double ece = 0.0;
#pragma unroll
      for (int b = 0; b < NACC; ++b) ece += fabs(ws->d[b] + (double)t[b]);
      out[0] = (float)(ece / (double)n);
      return;
    }
  }
#pragma unroll
  for (int off = 32; off > 0; off >>= 1) v += __shfl_down(v, off, 64);
  if (threadIdx.x == 0) out[0] = (float)(v / (double)n);
}

extern "C" void kernel_launch(void* const* d_in, const int* in_sizes, int n_in,
                              void* d_out, int out_size, void* d_ws, size_t ws_size,
                              hipStream_t stream) {
  const float4* logits4 = (const float4*)d_in[0];
  const int4* labels4 = (const int4*)d_in[1];
  const int n = in_sizes[1];  // rows == number of labels
  Accum* ws = (Accum*)d_ws;
  hipMemsetAsync(ws, 0, sizeof(Accum), stream);  // zero the 11 doubles
  ece_main<<<GRID, THREADS, 0, stream>>>(logits4, labels4, ws, n);
  ece_final<<<1, 64, 0, stream>>>(ws, (const float*)d_in[0], (const int*)d_in[1],
                                  (float*)d_out, n);
}

// Round 7
// 58.077 us; speedup vs baseline: 4.1826x; 1.1445x over previous
//
#include <hip/hip_runtime.h>
#include <math.h>

#define NBINS 15
#define THREADS 256
#define GRID 2048          // 8 blocks/CU * 256 CUs; exactly 8 iters/thread at N=2^24
#define BIN_LO 4           // C=3 => conf >= 1/3 => bins 4..14 only
#define NACC (NBINS - BIN_LO)

__device__ __forceinline__ void process_row(float l0, float l1, float l2, int lab,
                                            float* a) {
  float m  = fmaxf(fmaxf(l0, l1), l2);            // v_max3_f32
  float md = __builtin_amdgcn_fmed3f(l0, l1, l2); // median
  float mn = fminf(fminf(l0, l1), l2);            // v_min3_f32
  float s  = 1.0f + __expf(md - m) + __expf(mn - m);  // exp(max-max)=1 for free
  float conf = __builtin_amdgcn_rcpf(s);          // max prob = 1/s
  // correct <=> logit[label] equals the max (ties measure-zero; ECE effect ~6e-8)
  float lm = (lab == 1) ? l1 : ((lab == 2) ? l2 : l0);
  float val = conf - ((lm >= m) ? 1.0f : 0.0f);
  // bin i covers (i/15,(i+1)/15]; searchsorted(uppers,conf,'left') == ceil(conf*15)-1
  int bin = (int)ceilf(conf * 15.0f) - 1;
  bin = bin < BIN_LO ? BIN_LO : (bin > NBINS - 1 ? NBINS - 1 : bin);
#pragma unroll
  for (int b = BIN_LO; b < NBINS; ++b) a[b - BIN_LO] += (bin == b) ? val : 0.0f;
}

__global__ __launch_bounds__(THREADS, 8) void ece_main(
    const float4* __restrict__ logits4, const int4* __restrict__ labels4,
    float* __restrict__ partial, int n) {
  float a[NACC];
#pragma unroll
  for (int i = 0; i < NACC; ++i) a[i] = 0.0f;

  const int nquads = n >> 2;
  const int total = gridDim.x * blockDim.x;
  const int iters = nquads / total;  // uniform trip count (8 for N=2^24)
  int q = blockIdx.x * blockDim.x + threadIdx.x;
#pragma unroll 2
  for (int it = 0; it < iters; ++it, q += total) {
    const float4* p = logits4 + 3 * (size_t)q;
    float4 x = p[0], y = p[1], z = p[2];
    int4 lb = labels4[q];
    process_row(x.x, x.y, x.z, lb.x, a);
    process_row(x.w, y.x, y.y, lb.y, a);
    process_row(y.z, y.w, z.x, lb.z, a);
    process_row(z.y, z.z, z.w, lb.w, a);
  }
  if (q < nquads) {  // remainder quads when total doesn't divide nquads
    const float4* p = logits4 + 3 * (size_t)q;
    float4 x = p[0], y = p[1], z = p[2];
    int4 lb = labels4[q];
    process_row(x.x, x.y, x.z, lb.x, a);
    process_row(x.w, y.x, y.y, lb.y, a);
    process_row(y.z, y.w, z.x, lb.z, a);
    process_row(z.y, z.z, z.w, lb.w, a);
  }

  // wave butterfly reduce, then cross-wave via tiny LDS
#pragma unroll
  for (int i = 0; i < NACC; ++i) {
    float v = a[i];
#pragma unroll
    for (int off = 32; off > 0; off >>= 1) v += __shfl_down(v, off, 64);
    a[i] = v;
  }
  __shared__ float s_part[THREADS / 64][NACC];
  const int wave = threadIdx.x >> 6;
  const int lane = threadIdx.x & 63;
  if (lane == 0) {
#pragma unroll
    for (int i = 0; i < NACC; ++i) s_part[wave][i] = a[i];
  }
  __syncthreads();
  if (threadIdx.x < NACC) {
    float v = 0.0f;
#pragma unroll
    for (int w = 0; w < THREADS / 64; ++w) v += s_part[w][threadIdx.x];
    // [bin][block] layout: no atomics, no zero-init of ws needed
    partial[(size_t)threadIdx.x * gridDim.x + blockIdx.x] = v;
  }
}

__global__ __launch_bounds__(1024) void ece_final(
    const float* __restrict__ partial, const float* __restrict__ logits,
    const int* __restrict__ labels, float* __restrict__ out, int n, int nblocks) {
  __shared__ double sbin[NACC];
  const int wave = threadIdx.x >> 6;
  const int lane = threadIdx.x & 63;
  if (wave < NACC) {
    double v = 0.0;
    for (int i = lane; i < nblocks; i += 64)
      v += (double)partial[(size_t)wave * nblocks + i];
#pragma unroll
    for (int off = 32; off > 0; off >>= 1) v += __shfl_down(v, off, 64);
    if (lane == 0) sbin[wave] = v;
  }
  __syncthreads();
  if (threadIdx.x == 0) {
    float t[NACC];
#pragma unroll
    for (int i = 0; i < NACC; ++i) t[i] = 0.0f;
    for (int r = (n >> 2) << 2; r < n; ++r)  // tail rows (none for N=2^24)
      process_row(logits[3 * r], logits[3 * r + 1], logits[3 * r + 2], labels[r], t);
    double ece = 0.0;
#pragma unroll
    for (int b = 0; b < NACC; ++b) ece += fabs(sbin[b] + (double)t[b]);
    out[0] = (float)(ece / (double)n);
  }
}

extern "C" void kernel_launch(void* const* d_in, const int* in_sizes, int n_in,
                              void* d_out, int out_size, void* d_ws, size_t ws_size,
                              hipStream_t stream) {
  const float4* logits4 = (const float4*)d_in[0];
  const int4* labels4 = (const int4*)d_in[1];
  const int n = in_sizes[1];  // rows == number of labels
  float* partial = (float*)d_ws;  // [NACC][GRID] floats
  ece_main<<<GRID, THREADS, 0, stream>>>(logits4, labels4, partial, n);
  ece_final<<<1, 1024, 0, stream>>>(partial, (const float*)d_in[0],
                                    (const int*)d_in[1], (float*)d_out, n, GRID);
}